// Round 1
// baseline (219.654 us; speedup 1.0000x reference)
//
#include <hip/hip_runtime.h>

// DropConnectLinear: y[b,o] = sum_i x[b,i]*w[o,i]*(wmask[b,o,i]==0) + (bmask[b,o]==0)*bias[o]
// B=256, IN=1024, OUT=1024. Memory-bound on the 1 GB int32 weight_mask stream.

#define B_   256
#define IN_  1024
#define OUT_ 1024

__global__ __launch_bounds__(256) void dropconnect_kernel(
    const float* __restrict__ x,      // [B, IN]
    const float* __restrict__ w,      // [OUT, IN]
    const float* __restrict__ bias,   // [OUT]
    const int*   __restrict__ wmask,  // [B, OUT, IN] (0/1)
    const int*   __restrict__ bmask,  // [B, OUT]     (0/1)
    float*       __restrict__ out)    // [B, OUT]
{
    // one 64-lane wave per output element
    const int wave = blockIdx.x * (blockDim.x >> 6) + (threadIdx.x >> 6);
    const int lane = threadIdx.x & 63;
    const int b = wave >> 10;    // / OUT_
    const int o = wave & 1023;   // % OUT_

    const float4* xr = reinterpret_cast<const float4*>(x + (size_t)b * IN_);
    const float4* wr = reinterpret_cast<const float4*>(w + (size_t)o * IN_);
    const int4*   mr = reinterpret_cast<const int4*>(wmask + (size_t)wave * IN_);

    float acc = 0.0f;
    #pragma unroll
    for (int c = 0; c < 4; ++c) {
        const int idx = c * 64 + lane;   // lane-contiguous: 1 KB per load instruction
        const float4 xv = xr[idx];
        const float4 wv = wr[idx];
        const int4   mv = mr[idx];
        acc += (mv.x == 0) ? xv.x * wv.x : 0.0f;
        acc += (mv.y == 0) ? xv.y * wv.y : 0.0f;
        acc += (mv.z == 0) ? xv.z * wv.z : 0.0f;
        acc += (mv.w == 0) ? xv.w * wv.w : 0.0f;
    }

    // wave-wide sum (64 lanes)
    #pragma unroll
    for (int off = 32; off > 0; off >>= 1)
        acc += __shfl_down(acc, off, 64);

    if (lane == 0) {
        const float bv = (bmask[wave] != 0) ? 0.0f : bias[o];
        out[wave] = acc + bv;
    }
}

extern "C" void kernel_launch(void* const* d_in, const int* in_sizes, int n_in,
                              void* d_out, int out_size, void* d_ws, size_t ws_size,
                              hipStream_t stream) {
    const float* x     = (const float*)d_in[0];
    const float* w     = (const float*)d_in[1];
    const float* bias  = (const float*)d_in[2];
    const int*   wmask = (const int*)d_in[3];
    const int*   bmask = (const int*)d_in[4];
    float* out = (float*)d_out;

    const int total_waves = B_ * OUT_;          // 262144 output elements
    const int waves_per_block = 256 / 64;       // 4
    const int blocks = total_waves / waves_per_block;  // 65536

    dropconnect_kernel<<<blocks, 256, 0, stream>>>(x, w, bias, wmask, bmask, out);
}

// Round 2
// 193.842 us; speedup vs baseline: 1.1332x; 1.1332x over previous
//
#include <hip/hip_runtime.h>

// DropConnectLinear: y[b,o] = sum_i x[b,i]*w[o,i]*(wmask[b,o,i]==0) + (bmask[b,o]==0)*bias[o]
// B=256, IN=1024, OUT=1024. Memory-bound on the 1.07 GB int32 weight_mask stream.
// R2: nontemporal mask loads (keep w L2-resident), 2 outputs/wave (w reg-reuse),
//     split accumulators, shfl_xor reduce.

#define B_   256
#define IN_  1024
#define OUT_ 1024

typedef int   v4i __attribute__((ext_vector_type(4)));
typedef float v4f __attribute__((ext_vector_type(4)));

__global__ __launch_bounds__(256) void dropconnect_kernel(
    const float* __restrict__ x,      // [B, IN]
    const float* __restrict__ w,      // [OUT, IN]
    const float* __restrict__ bias,   // [OUT]
    const int*   __restrict__ wmask,  // [B, OUT, IN] (0/1)
    const int*   __restrict__ bmask,  // [B, OUT]     (0/1)
    float*       __restrict__ out)    // [B, OUT]
{
    // one 64-lane wave per TWO output elements: (b0, o) and (b0+1, o)
    const int wid  = blockIdx.x * (blockDim.x >> 6) + (threadIdx.x >> 6);
    const int lane = threadIdx.x & 63;
    const int bh = wid >> 10;     // 0..127  -> b0 = 2*bh
    const int o  = wid & 1023;
    const int b0 = bh << 1;

    const v4f* xr0 = reinterpret_cast<const v4f*>(x + (size_t)b0 * IN_);
    const v4f* xr1 = reinterpret_cast<const v4f*>(x + (size_t)(b0 + 1) * IN_);
    const v4f* wr  = reinterpret_cast<const v4f*>(w + (size_t)o * IN_);
    const v4i* mr0 = reinterpret_cast<const v4i*>(wmask + ((size_t)b0 * OUT_ + o) * IN_);
    const v4i* mr1 = reinterpret_cast<const v4i*>(wmask + ((size_t)(b0 + 1) * OUT_ + o) * IN_);

    float a0a = 0.f, a0b = 0.f;   // output 0: two chains
    float a1a = 0.f, a1b = 0.f;   // output 1: two chains

    #pragma unroll
    for (int c = 0; c < 4; ++c) {
        const int idx = c * 64 + lane;          // lane-contiguous: 1 KB / load instr
        const v4f wv = wr[idx];
        const v4f x0 = xr0[idx];
        const v4f x1 = xr1[idx];
        const v4i m0 = __builtin_nontemporal_load(mr0 + idx);
        const v4i m1 = __builtin_nontemporal_load(mr1 + idx);

        a0a = fmaf(x0[0], (m0[0] == 0) ? wv[0] : 0.f, a0a);
        a0b = fmaf(x0[1], (m0[1] == 0) ? wv[1] : 0.f, a0b);
        a0a = fmaf(x0[2], (m0[2] == 0) ? wv[2] : 0.f, a0a);
        a0b = fmaf(x0[3], (m0[3] == 0) ? wv[3] : 0.f, a0b);

        a1a = fmaf(x1[0], (m1[0] == 0) ? wv[0] : 0.f, a1a);
        a1b = fmaf(x1[1], (m1[1] == 0) ? wv[1] : 0.f, a1b);
        a1a = fmaf(x1[2], (m1[2] == 0) ? wv[2] : 0.f, a1a);
        a1b = fmaf(x1[3], (m1[3] == 0) ? wv[3] : 0.f, a1b);
    }

    float a0 = a0a + a0b;
    float a1 = a1a + a1b;

    // two independent butterfly reduces (chains interleave on the SIMD)
    #pragma unroll
    for (int off = 32; off > 0; off >>= 1) {
        a0 += __shfl_xor(a0, off, 64);
        a1 += __shfl_xor(a1, off, 64);
    }

    if (lane == 0) {
        const float bv = bias[o];
        const size_t e0 = (size_t)b0 * OUT_ + o;
        const size_t e1 = e0 + OUT_;
        out[e0] = a0 + ((bmask[e0] != 0) ? 0.f : bv);
        out[e1] = a1 + ((bmask[e1] != 0) ? 0.f : bv);
    }
}

extern "C" void kernel_launch(void* const* d_in, const int* in_sizes, int n_in,
                              void* d_out, int out_size, void* d_ws, size_t ws_size,
                              hipStream_t stream) {
    const float* x     = (const float*)d_in[0];
    const float* w     = (const float*)d_in[1];
    const float* bias  = (const float*)d_in[2];
    const int*   wmask = (const int*)d_in[3];
    const int*   bmask = (const int*)d_in[4];
    float* out = (float*)d_out;

    const int total_waves = (B_ / 2) * OUT_;           // 131072 waves, 2 outputs each
    const int waves_per_block = 256 / 64;              // 4
    const int blocks = total_waves / waves_per_block;  // 32768

    dropconnect_kernel<<<blocks, 256, 0, stream>>>(x, w, bias, wmask, bmask, out);
}

// Round 3
// 182.008 us; speedup vs baseline: 1.2068x; 1.0650x over previous
//
#include <hip/hip_runtime.h>

// DropConnectLinear: y[b,o] = sum_i x[b,i]*w[o,i]*(wmask[b,o,i]==0) + (bmask[b,o]==0)*bias[o]
// B=256, IN=1024, OUT=1024. Memory-bound on the 1.07 GB int32 weight_mask stream.
// R3: 4 outputs (4 b's) per wave -> w row loaded once per 16 KB of mask,
//     16-deep load stream per unroll step, 4 independent acc/reduce chains.
//     Mask loads nontemporal (evict-first, keep w/x cache-resident).

#define B_   256
#define IN_  1024
#define OUT_ 1024

typedef int   v4i __attribute__((ext_vector_type(4)));
typedef float v4f __attribute__((ext_vector_type(4)));

__global__ __launch_bounds__(256) void dropconnect_kernel(
    const float* __restrict__ x,      // [B, IN]
    const float* __restrict__ w,      // [OUT, IN]
    const float* __restrict__ bias,   // [OUT]
    const int*   __restrict__ wmask,  // [B, OUT, IN] (0/1)
    const int*   __restrict__ bmask,  // [B, OUT]     (0/1)
    float*       __restrict__ out)    // [B, OUT]
{
    // one 64-lane wave per FOUR output elements: (b0..b0+3, o)
    const int wid  = blockIdx.x * (blockDim.x >> 6) + (threadIdx.x >> 6);
    const int lane = threadIdx.x & 63;
    const int bq = wid >> 10;     // 0..63  -> b0 = 4*bq
    const int o  = wid & 1023;
    const int b0 = bq << 2;

    const v4f* wr  = reinterpret_cast<const v4f*>(w + (size_t)o * IN_);
    const v4f* xr0 = reinterpret_cast<const v4f*>(x + (size_t)(b0 + 0) * IN_);
    const v4f* xr1 = reinterpret_cast<const v4f*>(x + (size_t)(b0 + 1) * IN_);
    const v4f* xr2 = reinterpret_cast<const v4f*>(x + (size_t)(b0 + 2) * IN_);
    const v4f* xr3 = reinterpret_cast<const v4f*>(x + (size_t)(b0 + 3) * IN_);
    const size_t mbase = ((size_t)b0 * OUT_ + o) * IN_;
    const v4i* mr0 = reinterpret_cast<const v4i*>(wmask + mbase);
    const v4i* mr1 = reinterpret_cast<const v4i*>(wmask + mbase + (size_t)OUT_ * IN_);
    const v4i* mr2 = reinterpret_cast<const v4i*>(wmask + mbase + (size_t)2 * OUT_ * IN_);
    const v4i* mr3 = reinterpret_cast<const v4i*>(wmask + mbase + (size_t)3 * OUT_ * IN_);

    float a0a = 0.f, a0b = 0.f;
    float a1a = 0.f, a1b = 0.f;
    float a2a = 0.f, a2b = 0.f;
    float a3a = 0.f, a3b = 0.f;

    #pragma unroll
    for (int c = 0; c < 4; ++c) {
        const int idx = c * 64 + lane;          // lane-contiguous: 1 KB / load instr
        const v4f wv = wr[idx];
        const v4f x0 = xr0[idx];
        const v4f x1 = xr1[idx];
        const v4f x2 = xr2[idx];
        const v4f x3 = xr3[idx];
        const v4i m0 = __builtin_nontemporal_load(mr0 + idx);
        const v4i m1 = __builtin_nontemporal_load(mr1 + idx);
        const v4i m2 = __builtin_nontemporal_load(mr2 + idx);
        const v4i m3 = __builtin_nontemporal_load(mr3 + idx);

        a0a = fmaf(x0[0], (m0[0] == 0) ? wv[0] : 0.f, a0a);
        a0b = fmaf(x0[1], (m0[1] == 0) ? wv[1] : 0.f, a0b);
        a0a = fmaf(x0[2], (m0[2] == 0) ? wv[2] : 0.f, a0a);
        a0b = fmaf(x0[3], (m0[3] == 0) ? wv[3] : 0.f, a0b);

        a1a = fmaf(x1[0], (m1[0] == 0) ? wv[0] : 0.f, a1a);
        a1b = fmaf(x1[1], (m1[1] == 0) ? wv[1] : 0.f, a1b);
        a1a = fmaf(x1[2], (m1[2] == 0) ? wv[2] : 0.f, a1a);
        a1b = fmaf(x1[3], (m1[3] == 0) ? wv[3] : 0.f, a1b);

        a2a = fmaf(x2[0], (m2[0] == 0) ? wv[0] : 0.f, a2a);
        a2b = fmaf(x2[1], (m2[1] == 0) ? wv[1] : 0.f, a2b);
        a2a = fmaf(x2[2], (m2[2] == 0) ? wv[2] : 0.f, a2a);
        a2b = fmaf(x2[3], (m2[3] == 0) ? wv[3] : 0.f, a2b);

        a3a = fmaf(x3[0], (m3[0] == 0) ? wv[0] : 0.f, a3a);
        a3b = fmaf(x3[1], (m3[1] == 0) ? wv[1] : 0.f, a3b);
        a3a = fmaf(x3[2], (m3[2] == 0) ? wv[2] : 0.f, a3a);
        a3b = fmaf(x3[3], (m3[3] == 0) ? wv[3] : 0.f, a3b);
    }

    float a0 = a0a + a0b;
    float a1 = a1a + a1b;
    float a2 = a2a + a2b;
    float a3 = a3a + a3b;

    // four independent butterfly reduces (interleave on the SIMD)
    #pragma unroll
    for (int off = 32; off > 0; off >>= 1) {
        a0 += __shfl_xor(a0, off, 64);
        a1 += __shfl_xor(a1, off, 64);
        a2 += __shfl_xor(a2, off, 64);
        a3 += __shfl_xor(a3, off, 64);
    }

    if (lane == 0) {
        const float bv = bias[o];
        const size_t e0 = (size_t)b0 * OUT_ + o;
        out[e0]            = a0 + ((bmask[e0]            != 0) ? 0.f : bv);
        out[e0 + OUT_]     = a1 + ((bmask[e0 + OUT_]     != 0) ? 0.f : bv);
        out[e0 + 2 * OUT_] = a2 + ((bmask[e0 + 2 * OUT_] != 0) ? 0.f : bv);
        out[e0 + 3 * OUT_] = a3 + ((bmask[e0 + 3 * OUT_] != 0) ? 0.f : bv);
    }
}

extern "C" void kernel_launch(void* const* d_in, const int* in_sizes, int n_in,
                              void* d_out, int out_size, void* d_ws, size_t ws_size,
                              hipStream_t stream) {
    const float* x     = (const float*)d_in[0];
    const float* w     = (const float*)d_in[1];
    const float* bias  = (const float*)d_in[2];
    const int*   wmask = (const int*)d_in[3];
    const int*   bmask = (const int*)d_in[4];
    float* out = (float*)d_out;

    const int total_waves = (B_ / 4) * OUT_;           // 65536 waves, 4 outputs each
    const int waves_per_block = 256 / 64;              // 4
    const int blocks = total_waves / waves_per_block;  // 16384

    dropconnect_kernel<<<blocks, 256, 0, stream>>>(x, w, bias, wmask, bmask, out);
}

// Round 4
// 178.870 us; speedup vs baseline: 1.2280x; 1.0175x over previous
//
#include <hip/hip_runtime.h>

// DropConnectLinear: y[b,o] = sum_i x[b,i]*w[o,i]*(wmask[b,o,i]==0) + (bmask[b,o]==0)*bias[o]
// B=256, IN=1024, OUT=1024. Memory-bound on the 1.07 GB int32 weight_mask stream.
// R4: 8 outputs (8 b's) per wave -> w row loaded once per 32 KB of mask,
//     17 loads in flight per unroll step, 8 independent acc chains (one per output).
//     Mask loads nontemporal. All arrays statically indexed (full unroll).

#define B_   256
#define IN_  1024
#define OUT_ 1024
#define NB   8     // b's per wave

typedef int   v4i __attribute__((ext_vector_type(4)));
typedef float v4f __attribute__((ext_vector_type(4)));

__global__ __launch_bounds__(256) void dropconnect_kernel(
    const float* __restrict__ x,      // [B, IN]
    const float* __restrict__ w,      // [OUT, IN]
    const float* __restrict__ bias,   // [OUT]
    const int*   __restrict__ wmask,  // [B, OUT, IN] (0/1)
    const int*   __restrict__ bmask,  // [B, OUT]     (0/1)
    float*       __restrict__ out)    // [B, OUT]
{
    // one 64-lane wave per NB output elements: (b0..b0+NB-1, o)
    const int wid  = blockIdx.x * (blockDim.x >> 6) + (threadIdx.x >> 6);
    const int lane = threadIdx.x & 63;
    const int bg = wid >> 10;     // b-group  -> b0 = NB*bg
    const int o  = wid & 1023;
    const int b0 = bg * NB;

    const v4f* wr = reinterpret_cast<const v4f*>(w + (size_t)o * IN_);

    const v4f* xr[NB];
    const v4i* mr[NB];
    #pragma unroll
    for (int r = 0; r < NB; ++r) {
        xr[r] = reinterpret_cast<const v4f*>(x + (size_t)(b0 + r) * IN_);
        mr[r] = reinterpret_cast<const v4i*>(wmask + ((size_t)(b0 + r) * OUT_ + o) * IN_);
    }

    float acc[NB];
    #pragma unroll
    for (int r = 0; r < NB; ++r) acc[r] = 0.f;

    #pragma unroll
    for (int c = 0; c < 4; ++c) {
        const int idx = c * 64 + lane;          // lane-contiguous: 1 KB / load instr
        const v4f wv = wr[idx];
        v4i m[NB];
        v4f xv[NB];
        #pragma unroll
        for (int r = 0; r < NB; ++r) {
            m[r]  = __builtin_nontemporal_load(mr[r] + idx);
            xv[r] = xr[r][idx];
        }
        #pragma unroll
        for (int r = 0; r < NB; ++r) {
            acc[r] = fmaf(xv[r][0], (m[r][0] == 0) ? wv[0] : 0.f, acc[r]);
            acc[r] = fmaf(xv[r][1], (m[r][1] == 0) ? wv[1] : 0.f, acc[r]);
            acc[r] = fmaf(xv[r][2], (m[r][2] == 0) ? wv[2] : 0.f, acc[r]);
            acc[r] = fmaf(xv[r][3], (m[r][3] == 0) ? wv[3] : 0.f, acc[r]);
        }
    }

    // NB independent butterfly reduces (interleave on the SIMD)
    #pragma unroll
    for (int off = 32; off > 0; off >>= 1) {
        #pragma unroll
        for (int r = 0; r < NB; ++r)
            acc[r] += __shfl_xor(acc[r], off, 64);
    }

    if (lane == 0) {
        const float bv = bias[o];
        const size_t e0 = (size_t)b0 * OUT_ + o;
        #pragma unroll
        for (int r = 0; r < NB; ++r) {
            const size_t e = e0 + (size_t)r * OUT_;
            out[e] = acc[r] + ((bmask[e] != 0) ? 0.f : bv);
        }
    }
}

extern "C" void kernel_launch(void* const* d_in, const int* in_sizes, int n_in,
                              void* d_out, int out_size, void* d_ws, size_t ws_size,
                              hipStream_t stream) {
    const float* x     = (const float*)d_in[0];
    const float* w     = (const float*)d_in[1];
    const float* bias  = (const float*)d_in[2];
    const int*   wmask = (const int*)d_in[3];
    const int*   bmask = (const int*)d_in[4];
    float* out = (float*)d_out;

    const int total_waves = (B_ / NB) * OUT_;          // 32768 waves, NB outputs each
    const int waves_per_block = 256 / 64;              // 4
    const int blocks = total_waves / waves_per_block;  // 8192

    dropconnect_kernel<<<blocks, 256, 0, stream>>>(x, w, bias, wmask, bmask, out);
}